// Round 5
// baseline (383.822 us; speedup 1.0000x reference)
//
#include <hip/hip_runtime.h>
#include <math.h>

#define BB 8
#define CC 64
#define HH 128
#define WW 128
#define EE 8
#define OO 64
#define HID 128
#define GATEC 96
#define NP 8     // patches per spatial dim
#define PP 16    // patch size

typedef __attribute__((ext_vector_type(8))) short bf16x8;
typedef __attribute__((ext_vector_type(4))) float f32x4;

static __device__ __forceinline__ unsigned short f2bf(float f) {
  unsigned int u = __builtin_bit_cast(unsigned int, f);
  unsigned int r = (u + 0x7FFFu + ((u >> 16) & 1u)) >> 16;   // RNE
  return (unsigned short)r;
}

// ---------------- Kernel A: router gates (f32) ----------------
__global__ __launch_bounds__(256) void gate_kernel(
    const float* __restrict__ x,
    const float* __restrict__ W1, const float* __restrict__ b1,
    const float* __restrict__ W2, const float* __restrict__ b2,
    float* __restrict__ probs) {
  int blk = blockIdx.x;        // b*64 + pi*8 + pj
  int b  = blk >> 6;
  int pi = (blk >> 3) & 7;
  int pj = blk & 7;
  int t  = threadIdx.x;

  __shared__ float ps[256];
  __shared__ float g[GATEC];
  __shared__ float hbuf[HID];
  __shared__ float lg[EE];

  {
    int c = t >> 2, q = t & 3;
    const float* xb = x + ((size_t)(b * CC + c) * HH + pi * PP + q * 4) * WW + pj * PP;
    float s = 0.f;
    for (int r = 0; r < 4; ++r)
      for (int col = 0; col < PP; ++col)
        s += xb[r * WW + col];
    ps[t] = s;
  }
  __syncthreads();
  if (t < CC) {
    g[t] = (ps[4*t] + ps[4*t+1] + ps[4*t+2] + ps[4*t+3]) * (1.f / 256.f);
  } else if (t < CC + 32) {
    int k = t - CC;
    int fi = k & 7, kind = k >> 3;
    float freq  = (float)(1 << fi);
    float coord = (kind < 2) ? ((pi + 0.5f) / 8.f) : ((pj + 0.5f) / 8.f);
    float a = 6.28318530717958647692f * freq * coord;
    g[t] = (kind & 1) ? cosf(a) : sinf(a);
  }
  __syncthreads();
  if (t < HID) {
    float acc = b1[t];
    const float* w = W1 + (size_t)t * GATEC;
    for (int c = 0; c < GATEC; ++c) acc += w[c] * g[c];
    hbuf[t] = fmaxf(acc, 0.f);
  }
  __syncthreads();
  if (t < EE) {
    float acc = b2[t];
    const float* w = W2 + (size_t)t * HID;
    for (int k = 0; k < HID; ++k) acc += w[k] * hbuf[k];
    lg[t] = acc;
  }
  __syncthreads();
  if (t < EE) {
    float m = lg[0];
    for (int e = 1; e < EE; ++e) m = fmaxf(m, lg[e]);
    float sum = 0.f;
    for (int e = 0; e < EE; ++e) sum += expf(lg[e] - m);
    probs[((size_t)(b * EE + t) * NP + pi) * NP + pj] = expf(lg[t] - m) / sum;
  }
}

// ---------------- Kernel P: pack weights f32 [e][o][c][3][3] -> bf16 [e][t][o][c] ---
__global__ __launch_bounds__(256) void pack_kernel(
    const float* __restrict__ We, unsigned short* __restrict__ wp) {
  int idx = blockIdx.x * 256 + threadIdx.x;
  if (idx >= EE * 9 * OO * CC) return;
  int c  = idx & 63;
  int o  = (idx >> 6) & 63;
  int et = idx >> 12;            // e*9 + t
  int t  = et % 9;
  int e  = et / 9;
  float v = We[(((size_t)(e * OO + o) * CC) + c) * 9 + t];
  wp[idx] = f2bf(v);
}

// ---------------- Kernel B: MFMA expert conv + gated combine ----------------
// block = (b, half-patch: 8 rows x 16 cols). 4 waves; wave w = 64 o x 32 px
// (2 rows w*2,w*2+1 x 16 cols). Per iter: aw[4] (global), bx[2] (LDS), 8 MFMA.
// D = A(weights 16o x 32c) * B(x 32c x 16px): col=px=l&15, o=ot*16+kg*4+r.
__global__ __launch_bounds__(256, 4) void conv_moe(
    const float* __restrict__ x,
    const unsigned short* __restrict__ wp,   // [e][t][o][c] bf16, flat taps
    const float* __restrict__ be,
    const float* __restrict__ probs, float* __restrict__ out) {
  int bx0  = blockIdx.x;           // patch*2 + half
  int b    = blockIdx.y;
  int patch = bx0 >> 1, half = bx0 & 1;
  int pi = patch >> 3, pj = patch & 7;
  const int h0 = pi * PP + half * 8;   // first output row of this block (8 rows)
  const int w0 = pj * PP;

  int lane = threadIdx.x & 63;
  int wave = threadIdx.x >> 6;     // 0..3
  int px   = lane & 15;
  int kg   = lane >> 4;            // 0..3

  // halo: 10 rows x 18 cols x 64c bf16, chunk-of-8 16B slots,
  // slot-swizzled: lds[sp][(j ^ g)*16] = c-chunk j, g=(gr+gc)&7
  __shared__ bf16x8 xs_v[180 * 8];
  char* xs = (char*)xs_v;

  for (int i = 0; i < 6; ++i) {
    int unit = i * 256 + threadIdx.x;
    if (unit < 1440) {
      int sp = unit % 180;
      int j  = unit / 180;             // content chunk 0..7 (c = j*8..j*8+7)
      int r = sp / 18, col = sp % 18;
      int gr = h0 + r - 1, gc = w0 + col - 1;
      bf16x8 v;
      if (gr >= 0 && gr < HH && gc >= 0 && gc < WW) {
        const float* xb = x + ((size_t)(b * CC + j * 8) * HH + gr) * WW + gc;
#pragma unroll
        for (int q = 0; q < 8; ++q) v[q] = (short)f2bf(xb[(size_t)q * HH * WW]);
      } else {
#pragma unroll
        for (int q = 0; q < 8; ++q) v[q] = 0;
      }
      int g = (gr + gc) & 7;
      *(bf16x8*)(xs + sp * 128 + ((j ^ g) & 7) * 16) = v;
    }
  }
  __syncthreads();

  // per-lane weight offset inside a 4096-elem tap block: (o16=px)*64 + kg*8
  const unsigned short* wlane = wp + px * CC + kg * 8;
  const int rowbase = wave * 2;
  const char* xrow = xs + (rowbase * 18 + px) * 128;
  const int gl = h0 + w0 - 2 + rowbase + px;   // g = (gl + pt+dy+dx)&7

  f32x4 outacc[4][2];
#pragma unroll
  for (int ot = 0; ot < 4; ++ot)
#pragma unroll
    for (int pt = 0; pt < 2; ++pt) outacc[ot][pt] = (f32x4)(0.f);

  bf16x8 awc[4], awn[4];
#pragma unroll
  for (int ot = 0; ot < 4; ++ot)               // preload n=0 (tap 0, ks 0)
    awc[ot] = *(const bf16x8*)(wlane + ot * 1024);

  for (int e = 0; e < EE; ++e) {
    f32x4 acc[4][2];
#pragma unroll
    for (int ot = 0; ot < 4; ++ot)
#pragma unroll
      for (int pt = 0; pt < 2; ++pt) acc[ot][pt] = (f32x4)(0.f);

    const unsigned short* wbase_e = wlane + (size_t)e * 9 * 4096;

#pragma unroll
    for (int sub = 0; sub < 18; ++sub) {
      const int t9 = sub >> 1, ks = sub & 1;
      const int dy = t9 / 3, dx = t9 % 3;
      // ---- prefetch weights for iteration n+1 (crosses e-boundary naturally) ----
      const int ntap = (sub + 1) >> 1, nks = (sub + 1) & 1;
      if (sub < 17 || e < 7) {
#pragma unroll
        for (int ot = 0; ot < 4; ++ot)
          awn[ot] = *(const bf16x8*)(wbase_e + ntap * 4096 + ot * 1024 + nks * 32);
      }
      // ---- bx from LDS ----
      bf16x8 bxv[2];
#pragma unroll
      for (int pt = 0; pt < 2; ++pt) {
        int g = (gl + pt + dy + dx) & 7;
        int m = ks * 4 + kg;
        bxv[pt] = *(const bf16x8*)(xrow + ((pt + dy) * 18 + dx) * 128 + ((m ^ g) & 7) * 16);
      }
      // ---- 8 MFMA ----
#pragma unroll
      for (int ot = 0; ot < 4; ++ot)
#pragma unroll
        for (int pt = 0; pt < 2; ++pt)
          acc[ot][pt] = __builtin_amdgcn_mfma_f32_16x16x32_bf16(
              awc[ot], bxv[pt], acc[ot][pt], 0, 0, 0);
#pragma unroll
      for (int ot = 0; ot < 4; ++ot) awc[ot] = awn[ot];
    }

    // epilogue: bias + relu + gate-weighted accumulate
    float gt = probs[((size_t)(b * EE + e) * NP + pi) * NP + pj];
#pragma unroll
    for (int ot = 0; ot < 4; ++ot) {
      f32x4 bias = *(const f32x4*)(be + e * OO + ot * 16 + kg * 4);
#pragma unroll
      for (int pt = 0; pt < 2; ++pt) {
#pragma unroll
        for (int r = 0; r < 4; ++r)
          outacc[ot][pt][r] += gt * fmaxf(acc[ot][pt][r] + bias[r], 0.f);
      }
    }
  }

  // ---- store: lane holds o = ot*16+kg*4+r, col = px; NT to spare L2 ----
#pragma unroll
  for (int ot = 0; ot < 4; ++ot) {
#pragma unroll
    for (int pt = 0; pt < 2; ++pt) {
      int o = ot * 16 + kg * 4;
      int h = h0 + rowbase + pt;
      float* op = out + ((size_t)(b * OO + o) * HH + h) * WW + w0 + px;
#pragma unroll
      for (int r = 0; r < 4; ++r)
        __builtin_nontemporal_store(outacc[ot][pt][r], op + (size_t)r * HH * WW);
    }
  }
}

extern "C" void kernel_launch(void* const* d_in, const int* in_sizes, int n_in,
                              void* d_out, int out_size, void* d_ws, size_t ws_size,
                              hipStream_t stream) {
  const float* x  = (const float*)d_in[0];
  const float* We = (const float*)d_in[1];
  const float* be = (const float*)d_in[2];
  const float* W1 = (const float*)d_in[3];
  const float* b1 = (const float*)d_in[4];
  const float* W2 = (const float*)d_in[5];
  const float* b2 = (const float*)d_in[6];
  float* out = (float*)d_out;

  float* probs = (float*)d_ws;                                  // 16 KB
  unsigned short* wpk = (unsigned short*)((char*)d_ws + 16384); // 576 KB bf16 packed weights

  gate_kernel<<<dim3(BB * NP * NP), dim3(256), 0, stream>>>(x, W1, b1, W2, b2, probs);
  pack_kernel<<<dim3((EE * 9 * OO * CC + 255) / 256), dim3(256), 0, stream>>>(We, wpk);
  conv_moe<<<dim3(2 * NP * NP, BB), dim3(256), 0, stream>>>(x, wpk, be, probs, out);
}